// Round 5
// baseline (61.760 us; speedup 1.0000x reference)
//
#include <hip/hip_runtime.h>
#include <math.h>

#define BSZ 4
#define LEN_M 256
#define LEN_E 512
#define HDIM 512
#define KDIM 512
#define VOCAB 32000

typedef __attribute__((ext_vector_type(8))) short bf16x8;
typedef __attribute__((ext_vector_type(4))) float f32x4;

__device__ inline ushort f2bf(float x) {
    union { float f; unsigned u; } v; v.f = x;
    unsigned r = v.u + 0x7FFFu + ((v.u >> 16) & 1u);   // RNE
    return (ushort)(r >> 16);
}

// load 8 contiguous elements as bf16x8; F32 sources are converted on the fly
template<bool F32>
__device__ inline bf16x8 load8(const char* p) {
    if constexpr (F32) {
        const float4 v0 = ((const float4*)p)[0];
        const float4 v1 = ((const float4*)p)[1];
        bf16x8 r;
        r[0] = (short)f2bf(v0.x); r[1] = (short)f2bf(v0.y);
        r[2] = (short)f2bf(v0.z); r[3] = (short)f2bf(v0.w);
        r[4] = (short)f2bf(v1.x); r[5] = (short)f2bf(v1.y);
        r[6] = (short)f2bf(v1.z); r[7] = (short)f2bf(v1.w);
        return r;
    } else {
        return *(const bf16x8*)p;
    }
}

// ---- C[M][N] = scale * A[M][K] @ B[N][K]^T; bf16 MFMA; fp32 inputs staged ----
// 64x64 tile, 4 waves (2x2), each wave 32x32 = 2x2 frags of 16x16x32 MFMA.
// LROW=72 ushorts (144 B): 16B-aligned b128 ops, lanes spread over disjoint
// 4-bank groups -> at the wave64/b128 8-cycle floor (no extra conflicts).
#define LROW 72
template<bool A32, bool B32, bool OUT_BF16>
__global__ __launch_bounds__(256) void gemm_bt(const void* __restrict__ A,
                                               const void* __restrict__ B,
                                               void* __restrict__ C, int N,
                                               long sA, long sB, long sC,
                                               float scale) {
    __shared__ ushort As[64 * LROW];
    __shared__ ushort Bs[64 * LROW];
    const int t  = threadIdx.x;
    const int m0 = blockIdx.y * 64, n0 = blockIdx.x * 64;
    const size_t bz = blockIdx.z;
    const char* Ab = (const char*)A + bz * (size_t)sA * (A32 ? 4 : 2);
    const char* Bb = (const char*)B + bz * (size_t)sB * (B32 ? 4 : 2);

    const int wid = t >> 6, lane = t & 63;
    const int wr = wid >> 1, wc = wid & 1;
    const int lrow = lane & 15, lk = (lane >> 4) * 8;

    const int r0 = t >> 3;          // staging rows r0 and r0+32
    const int c8 = (t & 7) * 8;     // 8-element k-chunk

    bf16x8 pa0, pa1, pb0, pb1;
    f32x4 acc[2][2] = {};

    // prologue: K-tile 0
    pa0 = load8<A32>(Ab + ((size_t)(m0 + r0)      * KDIM + c8) * (A32 ? 4 : 2));
    pa1 = load8<A32>(Ab + ((size_t)(m0 + r0 + 32) * KDIM + c8) * (A32 ? 4 : 2));
    pb0 = load8<B32>(Bb + ((size_t)(n0 + r0)      * KDIM + c8) * (B32 ? 4 : 2));
    pb1 = load8<B32>(Bb + ((size_t)(n0 + r0 + 32) * KDIM + c8) * (B32 ? 4 : 2));
    *(bf16x8*)&As[(r0)      * LROW + c8] = pa0;
    *(bf16x8*)&As[(r0 + 32) * LROW + c8] = pa1;
    *(bf16x8*)&Bs[(r0)      * LROW + c8] = pb0;
    *(bf16x8*)&Bs[(r0 + 32) * LROW + c8] = pb1;
    __syncthreads();

    for (int kt = 0; kt < KDIM / 64; ++kt) {
        if (kt + 1 < KDIM / 64) {           // prefetch next K-tile into regs
            const int k0 = (kt + 1) * 64;
            pa0 = load8<A32>(Ab + ((size_t)(m0 + r0)      * KDIM + k0 + c8) * (A32 ? 4 : 2));
            pa1 = load8<A32>(Ab + ((size_t)(m0 + r0 + 32) * KDIM + k0 + c8) * (A32 ? 4 : 2));
            pb0 = load8<B32>(Bb + ((size_t)(n0 + r0)      * KDIM + k0 + c8) * (B32 ? 4 : 2));
            pb1 = load8<B32>(Bb + ((size_t)(n0 + r0 + 32) * KDIM + k0 + c8) * (B32 ? 4 : 2));
        }
#pragma unroll
        for (int ks = 0; ks < 2; ++ks) {
            bf16x8 af[2], bfr[2];
#pragma unroll
            for (int i = 0; i < 2; ++i)
                af[i]  = *(const bf16x8*)&As[(wr * 32 + i * 16 + lrow) * LROW + ks * 32 + lk];
#pragma unroll
            for (int j = 0; j < 2; ++j)
                bfr[j] = *(const bf16x8*)&Bs[(wc * 32 + j * 16 + lrow) * LROW + ks * 32 + lk];
#pragma unroll
            for (int i = 0; i < 2; ++i)
#pragma unroll
                for (int j = 0; j < 2; ++j)
                    acc[i][j] = __builtin_amdgcn_mfma_f32_16x16x32_bf16(af[i], bfr[j], acc[i][j], 0, 0, 0);
        }
        __syncthreads();
        if (kt + 1 < KDIM / 64) {
            *(bf16x8*)&As[(r0)      * LROW + c8] = pa0;
            *(bf16x8*)&As[(r0 + 32) * LROW + c8] = pa1;
            *(bf16x8*)&Bs[(r0)      * LROW + c8] = pb0;
            *(bf16x8*)&Bs[(r0 + 32) * LROW + c8] = pb1;
            __syncthreads();
        }
    }

    // epilogue: C/D layout (m89): col = lane&15, row = (lane>>4)*4 + reg
    const int crow = m0 + wr * 32 + (lane >> 4) * 4;
    const int ccol = n0 + wc * 32 + lrow;
#pragma unroll
    for (int i = 0; i < 2; ++i)
#pragma unroll
        for (int j = 0; j < 2; ++j)
#pragma unroll
            for (int r = 0; r < 4; ++r) {
                const size_t o = bz * (size_t)sC + (size_t)(crow + i * 16 + r) * N + ccol + j * 16;
                const float v = acc[i][j][r] * scale;
                if (OUT_BF16) ((ushort*)C)[o] = f2bf(v);
                else          ((float*)C)[o]  = v;
            }
}

// ---- lambda + dual softmax -> Val[bm][e] --------------------------------------
__global__ __launch_bounds__(512) void softmax_val(const float* __restrict__ Lg,
                                                   const float* __restrict__ bq,
                                                   const float* __restrict__ bc,
                                                   const float* __restrict__ D,
                                                   const float* __restrict__ Cq,
                                                   const float* __restrict__ Cc,
                                                   const float* __restrict__ Wl,
                                                   const float* __restrict__ bl,
                                                   float* __restrict__ Val) {
    const int bm = blockIdx.x;         // 0..BSZ*LEN_M-1
    const int b  = bm >> 8;            // LEN_M = 256
    const int e  = threadIdx.x;        // 0..511
    const int wid = e >> 6;

    __shared__ float sh[8], smq[8], smc[8], ssq[8], ssc[8];

    // lambda partial: sigmoid([D|Cq|Cc] . W_lambda + b)
    const size_t rb = (size_t)bm * HDIM + e;
    float ls = D[rb] * Wl[e] + Cq[rb] * Wl[HDIM + e] + Cc[rb] * Wl[2 * HDIM + e];
#pragma unroll
    for (int o = 32; o; o >>= 1) ls += __shfl_xor(ls, o);
    if ((e & 63) == 0) sh[wid] = ls;

    const float L  = Lg[(size_t)bm * LEN_E + e];
    const float xq = L + bq[b * LEN_E + e];
    const float xc = L + bc[b * LEN_E + e];

    // block max (both softmaxes at once)
    float mq = xq, mc = xc;
#pragma unroll
    for (int o = 32; o; o >>= 1) {
        mq = fmaxf(mq, __shfl_xor(mq, o));
        mc = fmaxf(mc, __shfl_xor(mc, o));
    }
    if ((e & 63) == 0) { smq[wid] = mq; smc[wid] = mc; }
    __syncthreads();
    float lsum = sh[0];
    mq = smq[0]; mc = smc[0];
#pragma unroll
    for (int i = 1; i < 8; ++i) {
        lsum += sh[i];
        mq = fmaxf(mq, smq[i]); mc = fmaxf(mc, smc[i]);
    }
    const float lam = 1.f / (1.f + expf(-(lsum + bl[0])));

    // exp + block sum
    const float pq = expf(xq - mq);
    const float pc = expf(xc - mc);
    float sq = pq, sc = pc;
#pragma unroll
    for (int o = 32; o; o >>= 1) {
        sq += __shfl_xor(sq, o);
        sc += __shfl_xor(sc, o);
    }
    if ((e & 63) == 0) { ssq[wid] = sq; ssc[wid] = sc; }
    __syncthreads();
    sq = ssq[0]; sc = ssc[0];
#pragma unroll
    for (int i = 1; i < 8; ++i) { sq += ssq[i]; sc += ssc[i]; }

    Val[(size_t)bm * LEN_E + e] = lam * (pq / sq) + (1.f - lam) * (pc / sc);
}

// ---- zero + scatter + stream one vocab chunk of one row ----------------------
#define CHUNK 8000          // 32 KB LDS -> ~5 blocks/CU, 20 waves
__global__ __launch_bounds__(256) void distribute(const float* __restrict__ Val,
                                                  const int* __restrict__ idx,
                                                  float* __restrict__ out) {
    __shared__ float buf[CHUNK];
    const int bm = blockIdx.x;          // row 0..1023
    const int c  = blockIdx.y;          // chunk 0..3
    const int b  = bm >> 8;
    const int t  = threadIdx.x;
    const int lo = c * CHUNK;

    // issue idx loads early (L2-resident, 8 KB total) while zeroing LDS
    const int v0 = idx[b * LEN_E + t]       - lo;
    const int v1 = idx[b * LEN_E + t + 256] - lo;

    for (int i = t; i < CHUNK / 4; i += 256)
        ((float4*)buf)[i] = make_float4(0.f, 0.f, 0.f, 0.f);
    __syncthreads();

    // scatter (LDS atomics resolve duplicate token ids within the chunk)
    if ((unsigned)v0 < (unsigned)CHUNK)
        atomicAdd(&buf[v0], Val[(size_t)bm * LEN_E + t]);
    if ((unsigned)v1 < (unsigned)CHUNK)
        atomicAdd(&buf[v1], Val[(size_t)bm * LEN_E + t + 256]);
    __syncthreads();

    // stream the chunk to global (pure float4 stores, no global atomics)
    float4* __restrict__ dst = (float4*)(out + (size_t)bm * VOCAB + lo);
    for (int i = t; i < CHUNK / 4; i += 256)
        dst[i] = ((const float4*)buf)[i];
}

extern "C" void kernel_launch(void* const* d_in, const int* in_sizes, int n_in,
                              void* d_out, int out_size, void* d_ws, size_t ws_size,
                              hipStream_t stream) {
    const int*   idx = (const int*)  d_in[0];
    const float* D   = (const float*)d_in[1];
    const float* Cq  = (const float*)d_in[2];
    const float* Cc  = (const float*)d_in[3];
    const float* Mm  = (const float*)d_in[4];
    const float* E   = (const float*)d_in[5];
    const float* bq  = (const float*)d_in[6];
    const float* bc  = (const float*)d_in[7];
    const float* Wl  = (const float*)d_in[8];
    const float* bl  = (const float*)d_in[9];
    const float* We  = (const float*)d_in[10];
    const float* Wm  = (const float*)d_in[11];
    float* out = (float*)d_out;

    // workspace (16B aligned)
    char* w = (char*)d_ws;
    ushort* W2T = (ushort*)w;  w += (size_t)512 * 512 * 2;    // (We @ Wm^T) * s, bf16
    ushort* T1  = (ushort*)w;  w += (size_t)1024 * 512 * 2;   // M @ W2T^T, bf16
    float*  Lg  = (float*)w;   w += (size_t)1024 * 512 * 4;   // logits, fp32
    float*  Val = (float*)w;                                  // gated probs

    // 1) W2T = (We @ Wm^T) * H^-0.5        [512 x 512]
    gemm_bt<true, true, true><<<dim3(8, 8, 1), 256, 0, stream>>>(
        We, Wm, W2T, 512, 0, 0, 0, 0.04419417382415922f);
    // 2) T1 = M @ W2T^T                    [1024 x 512]
    gemm_bt<true, false, true><<<dim3(8, 16, 1), 256, 0, stream>>>(
        Mm, W2T, T1, 512, 0, 0, 0, 1.0f);
    // 3) logits[b] = T1[b] @ E[b]^T        [4 x 256 x 512]
    gemm_bt<false, true, false><<<dim3(8, 4, BSZ), 256, 0, stream>>>(
        T1, E, Lg, 512, 256 * 512, 512 * 512, 256 * 512, 1.0f);
    // 4) lambda + dual softmax -> Val
    softmax_val<<<BSZ * LEN_M, LEN_E, 0, stream>>>(Lg, bq, bc, D, Cq, Cc, Wl, bl, Val);
    // 5) zero + scatter + stream
    distribute<<<dim3(BSZ * LEN_M, VOCAB / CHUNK), 256, 0, stream>>>(Val, idx, out);
}

// Round 6
// 57.425 us; speedup vs baseline: 1.0755x; 1.0755x over previous
//
#include <hip/hip_runtime.h>
#include <math.h>

#define BSZ 4
#define LEN_M 256
#define LEN_E 512
#define HDIM 512
#define KDIM 512
#define VOCAB 32000

typedef __attribute__((ext_vector_type(8))) short bf16x8;
typedef __attribute__((ext_vector_type(4))) float f32x4;

__device__ inline ushort f2bf(float x) {
    union { float f; unsigned u; } v; v.f = x;
    unsigned r = v.u + 0x7FFFu + ((v.u >> 16) & 1u);   // RNE
    return (ushort)(r >> 16);
}

// ---- bf16 A[M][K] @ B[N][K]^T core: 64x64 tile, 4 waves, 16x16x32 MFMA -------
// LROW=72 ushorts (144 B): 16B-aligned b128 ops, lanes spread over disjoint
// 4-bank groups -> at the wave64/b128 floor (no extra conflicts). Proven R3.
#define LROW 72
template<bool OUT_BF16>
__device__ __forceinline__ void gemm_core(const ushort* __restrict__ Ab,
                                          const ushort* __restrict__ Bb,
                                          void* __restrict__ Cb, int N, float scale,
                                          ushort* As, ushort* Bs, int m0, int n0) {
    const int t = threadIdx.x;
    const int wid = t >> 6, lane = t & 63;
    const int wr = wid >> 1, wc = wid & 1;
    const int lrow = lane & 15, lk = (lane >> 4) * 8;
    const int r0 = t >> 3;          // staging rows r0 and r0+32
    const int c8 = (t & 7) * 8;     // 8-element k-chunk

    bf16x8 pa0, pa1, pb0, pb1;
    f32x4 acc[2][2] = {};

    // prologue: K-tile 0
    pa0 = *(const bf16x8*)&Ab[(size_t)(m0 + r0)      * KDIM + c8];
    pa1 = *(const bf16x8*)&Ab[(size_t)(m0 + r0 + 32) * KDIM + c8];
    pb0 = *(const bf16x8*)&Bb[(size_t)(n0 + r0)      * KDIM + c8];
    pb1 = *(const bf16x8*)&Bb[(size_t)(n0 + r0 + 32) * KDIM + c8];
    *(bf16x8*)&As[(r0)      * LROW + c8] = pa0;
    *(bf16x8*)&As[(r0 + 32) * LROW + c8] = pa1;
    *(bf16x8*)&Bs[(r0)      * LROW + c8] = pb0;
    *(bf16x8*)&Bs[(r0 + 32) * LROW + c8] = pb1;
    __syncthreads();

    for (int kt = 0; kt < KDIM / 64; ++kt) {
        if (kt + 1 < KDIM / 64) {           // prefetch next K-tile into regs
            const int k0 = (kt + 1) * 64;
            pa0 = *(const bf16x8*)&Ab[(size_t)(m0 + r0)      * KDIM + k0 + c8];
            pa1 = *(const bf16x8*)&Ab[(size_t)(m0 + r0 + 32) * KDIM + k0 + c8];
            pb0 = *(const bf16x8*)&Bb[(size_t)(n0 + r0)      * KDIM + k0 + c8];
            pb1 = *(const bf16x8*)&Bb[(size_t)(n0 + r0 + 32) * KDIM + k0 + c8];
        }
#pragma unroll
        for (int ks = 0; ks < 2; ++ks) {
            bf16x8 af[2], bfr[2];
#pragma unroll
            for (int i = 0; i < 2; ++i)
                af[i]  = *(const bf16x8*)&As[(wr * 32 + i * 16 + lrow) * LROW + ks * 32 + lk];
#pragma unroll
            for (int j = 0; j < 2; ++j)
                bfr[j] = *(const bf16x8*)&Bs[(wc * 32 + j * 16 + lrow) * LROW + ks * 32 + lk];
#pragma unroll
            for (int i = 0; i < 2; ++i)
#pragma unroll
                for (int j = 0; j < 2; ++j)
                    acc[i][j] = __builtin_amdgcn_mfma_f32_16x16x32_bf16(af[i], bfr[j], acc[i][j], 0, 0, 0);
        }
        __syncthreads();
        if (kt + 1 < KDIM / 64) {
            *(bf16x8*)&As[(r0)      * LROW + c8] = pa0;
            *(bf16x8*)&As[(r0 + 32) * LROW + c8] = pa1;
            *(bf16x8*)&Bs[(r0)      * LROW + c8] = pb0;
            *(bf16x8*)&Bs[(r0 + 32) * LROW + c8] = pb1;
            __syncthreads();
        }
    }

    // epilogue: C/D layout (m89): col = lane&15, row = (lane>>4)*4 + reg
    const int crow = m0 + wr * 32 + (lane >> 4) * 4;
    const int ccol = n0 + wc * 32 + lrow;
#pragma unroll
    for (int i = 0; i < 2; ++i)
#pragma unroll
        for (int j = 0; j < 2; ++j)
#pragma unroll
            for (int r = 0; r < 4; ++r) {
                const size_t o = (size_t)(crow + i * 16 + r) * N + ccol + j * 16;
                const float v = acc[i][j][r] * scale;
                if (OUT_BF16) ((ushort*)Cb)[o] = f2bf(v);
                else          ((float*)Cb)[o]  = v;
            }
}

// ---- convert M,E -> bf16 (elementwise) and We,Wm -> bf16 TRANSPOSED ----------
// blocks 0..1535: elementwise float4 (M: 131072 f4, E: 262144 f4)
// blocks 1536..1663: 64x64 tile transposes (64 tiles per weight matrix)
__global__ __launch_bounds__(256) void convert_tr(const float* __restrict__ M_,
                                                  const float* __restrict__ E_,
                                                  const float* __restrict__ We_,
                                                  const float* __restrict__ Wm_,
                                                  ushort* __restrict__ Mbf,
                                                  ushort* __restrict__ Ebf,
                                                  ushort* __restrict__ WeT,
                                                  ushort* __restrict__ WmT) {
    __shared__ ushort Ts[64][68];
    const int blk = blockIdx.x;
    if (blk < 1536) {
        const int i4 = blk * 256 + threadIdx.x;   // 0..393215
        const float* src; ushort* dst; int off;
        if (i4 < 131072) { src = M_; dst = Mbf; off = 0; }
        else             { src = E_; dst = Ebf; off = 131072; }
        const int j = i4 - off;
        const float4 v = ((const float4*)src)[j];
        ushort4 o; o.x = f2bf(v.x); o.y = f2bf(v.y); o.z = f2bf(v.z); o.w = f2bf(v.w);
        ((ushort4*)dst)[j] = o;
    } else {
        const int ti  = blk - 1536;          // 0..127
        const int mat = ti >> 6;             // 0: We, 1: Wm
        const int tt  = ti & 63;
        const int kt  = tt >> 3, nt = tt & 7;
        const float* W = mat ? Wm_ : We_;
        ushort* WT     = mat ? WmT : WeT;
        const int r = threadIdx.x >> 4, c4 = (threadIdx.x & 15) * 4;
#pragma unroll
        for (int p = 0; p < 4; ++p) {
            const int row = r + p * 16;
            const float4 v = *(const float4*)&W[(size_t)(kt * 64 + row) * HDIM + nt * 64 + c4];
            Ts[row][c4 + 0] = f2bf(v.x); Ts[row][c4 + 1] = f2bf(v.y);
            Ts[row][c4 + 2] = f2bf(v.z); Ts[row][c4 + 3] = f2bf(v.w);
        }
        __syncthreads();
#pragma unroll
        for (int p = 0; p < 4; ++p) {
            const int row = r + p * 16;      // row within the n-tile of WT
            ushort4 o;
            o.x = Ts[c4 + 0][row]; o.y = Ts[c4 + 1][row];
            o.z = Ts[c4 + 2][row]; o.w = Ts[c4 + 3][row];
            *(ushort4*)&WT[(size_t)(nt * 64 + row) * HDIM + kt * 64 + c4] = o;
        }
    }
}

// ---- Ep = E @ We and Mp = s * (M @ Wm) in ONE launch (independent GEMMs) ------
__global__ __launch_bounds__(256) void gemm_epmp(const ushort* __restrict__ Ebf,
                                                 const ushort* __restrict__ Mbf,
                                                 const ushort* __restrict__ WeT,
                                                 const ushort* __restrict__ WmT,
                                                 ushort* __restrict__ Ep,
                                                 ushort* __restrict__ Mp) {
    __shared__ ushort As[64 * LROW];
    __shared__ ushort Bs[64 * LROW];
    const int by = blockIdx.y;          // 0..47: 0-31 Ep tiles, 32-47 Mp tiles
    const int n0 = blockIdx.x * 64;
    if (by < 32) {
        gemm_core<true>(Ebf + (size_t)by * 64 * KDIM, WeT,
                        (void*)(Ep + (size_t)by * 64 * HDIM), HDIM, 1.0f,
                        As, Bs, 0, n0);
    } else {
        gemm_core<true>(Mbf + (size_t)(by - 32) * 64 * KDIM, WmT,
                        (void*)(Mp + (size_t)(by - 32) * 64 * HDIM), HDIM,
                        0.04419417382415922f, As, Bs, 0, n0);
    }
}

// ---- logits[b] = Mp[b] @ Ep[b]^T ----------------------------------------------
__global__ __launch_bounds__(256) void gemm_lg(const ushort* __restrict__ Mp,
                                               const ushort* __restrict__ Ep,
                                               float* __restrict__ Lg) {
    __shared__ ushort As[64 * LROW];
    __shared__ ushort Bs[64 * LROW];
    const size_t b = blockIdx.z;
    gemm_core<false>(Mp + b * LEN_M * KDIM, Ep + b * LEN_E * KDIM,
                     (void*)(Lg + b * LEN_M * LEN_E), LEN_E, 1.0f,
                     As, Bs, blockIdx.y * 64, blockIdx.x * 64);
}

// ---- lambda + dual softmax -> Val[bm][e] --------------------------------------
__global__ __launch_bounds__(512) void softmax_val(const float* __restrict__ Lg,
                                                   const float* __restrict__ bq,
                                                   const float* __restrict__ bc,
                                                   const float* __restrict__ D,
                                                   const float* __restrict__ Cq,
                                                   const float* __restrict__ Cc,
                                                   const float* __restrict__ Wl,
                                                   const float* __restrict__ bl,
                                                   float* __restrict__ Val) {
    const int bm = blockIdx.x;         // 0..BSZ*LEN_M-1
    const int b  = bm >> 8;            // LEN_M = 256
    const int e  = threadIdx.x;        // 0..511
    const int wid = e >> 6;

    __shared__ float sh[8], smq[8], smc[8], ssq[8], ssc[8];

    // lambda partial: sigmoid([D|Cq|Cc] . W_lambda + b)
    const size_t rb = (size_t)bm * HDIM + e;
    float ls = D[rb] * Wl[e] + Cq[rb] * Wl[HDIM + e] + Cc[rb] * Wl[2 * HDIM + e];
#pragma unroll
    for (int o = 32; o; o >>= 1) ls += __shfl_xor(ls, o);
    if ((e & 63) == 0) sh[wid] = ls;

    const float L  = Lg[(size_t)bm * LEN_E + e];
    const float xq = L + bq[b * LEN_E + e];
    const float xc = L + bc[b * LEN_E + e];

    // block max (both softmaxes at once)
    float mq = xq, mc = xc;
#pragma unroll
    for (int o = 32; o; o >>= 1) {
        mq = fmaxf(mq, __shfl_xor(mq, o));
        mc = fmaxf(mc, __shfl_xor(mc, o));
    }
    if ((e & 63) == 0) { smq[wid] = mq; smc[wid] = mc; }
    __syncthreads();
    float lsum = sh[0];
    mq = smq[0]; mc = smc[0];
#pragma unroll
    for (int i = 1; i < 8; ++i) {
        lsum += sh[i];
        mq = fmaxf(mq, smq[i]); mc = fmaxf(mc, smc[i]);
    }
    const float lam = 1.f / (1.f + expf(-(lsum + bl[0])));

    // exp + block sum
    const float pq = expf(xq - mq);
    const float pc = expf(xc - mc);
    float sq = pq, sc = pc;
#pragma unroll
    for (int o = 32; o; o >>= 1) {
        sq += __shfl_xor(sq, o);
        sc += __shfl_xor(sc, o);
    }
    if ((e & 63) == 0) { ssq[wid] = sq; ssc[wid] = sc; }
    __syncthreads();
    sq = ssq[0]; sc = ssc[0];
#pragma unroll
    for (int i = 1; i < 8; ++i) { sq += ssq[i]; sc += ssc[i]; }

    Val[(size_t)bm * LEN_E + e] = lam * (pq / sq) + (1.f - lam) * (pc / sc);
}

// ---- zero + scatter + stream one vocab chunk of one row ----------------------
#define CHUNK 8000          // 32 KB LDS
__global__ __launch_bounds__(512) void distribute(const float* __restrict__ Val,
                                                  const int* __restrict__ idx,
                                                  float* __restrict__ out) {
    __shared__ float buf[CHUNK];
    const int bm = blockIdx.x;          // row 0..1023
    const int c  = blockIdx.y;          // chunk 0..3
    const int b  = bm >> 8;
    const int t  = threadIdx.x;         // 0..511 -> one scatter entry each
    const int lo = c * CHUNK;

    // issue idx load early (L2-resident) while zeroing LDS
    const int v0 = idx[b * LEN_E + t] - lo;

    for (int i = t; i < CHUNK / 4; i += 512)
        ((f32x4*)buf)[i] = (f32x4){0.f, 0.f, 0.f, 0.f};
    __syncthreads();

    // scatter (LDS atomics resolve duplicate token ids within the chunk)
    if ((unsigned)v0 < (unsigned)CHUNK)
        atomicAdd(&buf[v0], Val[(size_t)bm * LEN_E + t]);
    __syncthreads();

    // stream the chunk to global: nontemporal float4 (write-once, bypass L2)
    f32x4* __restrict__ dst = (f32x4*)(out + (size_t)bm * VOCAB + lo);
    for (int i = t; i < CHUNK / 4; i += 512)
        __builtin_nontemporal_store(((const f32x4*)buf)[i], dst + i);
}

extern "C" void kernel_launch(void* const* d_in, const int* in_sizes, int n_in,
                              void* d_out, int out_size, void* d_ws, size_t ws_size,
                              hipStream_t stream) {
    const int*   idx = (const int*)  d_in[0];
    const float* D   = (const float*)d_in[1];
    const float* Cq  = (const float*)d_in[2];
    const float* Cc  = (const float*)d_in[3];
    const float* Mm  = (const float*)d_in[4];
    const float* E   = (const float*)d_in[5];
    const float* bq  = (const float*)d_in[6];
    const float* bc  = (const float*)d_in[7];
    const float* Wl  = (const float*)d_in[8];
    const float* bl  = (const float*)d_in[9];
    const float* We  = (const float*)d_in[10];
    const float* Wm  = (const float*)d_in[11];
    float* out = (float*)d_out;

    // workspace (16B aligned), ~11 MB total
    char* w = (char*)d_ws;
    ushort* Mbf = (ushort*)w;  w += (size_t)1024 * 512 * 2;   // M bf16
    ushort* Ebf = (ushort*)w;  w += (size_t)2048 * 512 * 2;   // E bf16
    ushort* WeT = (ushort*)w;  w += (size_t)512 * 512 * 2;    // We^T bf16
    ushort* WmT = (ushort*)w;  w += (size_t)512 * 512 * 2;    // Wm^T bf16
    ushort* Ep  = (ushort*)w;  w += (size_t)2048 * 512 * 2;   // E @ We, bf16
    ushort* Mp  = (ushort*)w;  w += (size_t)1024 * 512 * 2;   // s * M @ Wm, bf16
    float*  Lg  = (float*)w;   w += (size_t)1024 * 512 * 4;   // logits fp32
    float*  Val = (float*)w;                                  // gated probs fp32

    // 1) fp32 -> bf16 (M, E elementwise; We, Wm transposed)
    convert_tr<<<1664, 256, 0, stream>>>(Mm, E, We, Wm, Mbf, Ebf, WeT, WmT);
    // 2) Ep = E @ We  and  Mp = H^-0.5 * (M @ Wm)   -- one launch, 384 blocks
    gemm_epmp<<<dim3(8, 48), 256, 0, stream>>>(Ebf, Mbf, WeT, WmT, Ep, Mp);
    // 3) logits[b] = Mp[b] @ Ep[b]^T                -- 128 blocks
    gemm_lg<<<dim3(8, 4, BSZ), 256, 0, stream>>>(Mp, Ep, Lg);
    // 4) lambda + dual softmax -> Val
    softmax_val<<<BSZ * LEN_M, LEN_E, 0, stream>>>(Lg, bq, bc, D, Cq, Cc, Wl, bl, Val);
    // 5) zero + scatter + stream
    distribute<<<dim3(BSZ * LEN_M, VOCAB / CHUNK), 512, 0, stream>>>(Val, idx, out);
}